// Round 20
// baseline (28.908 us; speedup 1.0000x reference)
//
#include <hip/hip_runtime.h>

// PixelEffectModule: 8-bin intensity histogram over 11x11 windows at stride 8,
// argmax bin, output that bin's mean RGB, upsampled 8x8.
// Input: rgb (1,3,2048,2048) fp32 in [0,255). Output: (1,3,2048,2048) fp32.
//
// R20: progressive counted-vmcnt, zero barriers. R13-R19 showed the
// stage->FULL-drain->compute schedule plateaus at ~25 us (no pipe >35%).
// Root cause: R14's part->rows mapping needs the LAST staged row before the
// FIRST read. Fix: row-ordered consumption.
//  - wave = 16 cells x 4 row-subs (sub s: rows 4k+s, k=0..2; sets
//    {0,4,8},{1,5,9},{2,6,10},{3,7}); rows staged row-major -> 3 progressive
//    steps: vmcnt(13)/rows 0-3, vmcnt(6)/rows 4-7, vmcnt(0)/rows 8-10.
//    Compute on early rows overlaps arrival of late rows IN THE SAME WAVE.
//  - waves independent: each of 2 waves/WG stages its own 16-cell tile into
//    its own 20 KB buffer; reduces = shfl_xor(16/32). ZERO barriers.
//  - PITCH=37 (odd): subs' row-bases alternate parity; each sub's 16
//    stride-2 lanes fill one parity class -> exactly 8 lanes/bank-group
//    (wave64 floor) by construction, no swizzle.
//  - math path = R14's verified two-pass nibble (absmax 0.0 lineage).
// Tripwires: absmax != 0 -> mapping bug, revert; dur >= 25 -> concede
// plateau (R14/R19); WRITE > 60 MB -> spill.

#define Wd 2048
#define HW (2048 * 2048)
#define CPRo 36             // real 16B chunks per (row,ch) span (144 floats)
#define PITCH 37            // LDS slots per (row,ch) block (pad slot 36)
#define NBLK 33             // 11 rows x 3 channels, row-major (r*3+ch)
#define NSLOT (NBLK * PITCH)   // 1221
#define ITERS 20               // 20 x 64 = 1280 slots (59 tail-pad)
#define BUF_F (1280 * 4)       // 20,480 B per wave buffer

typedef unsigned int u32;
typedef unsigned long long u64;
typedef float f32x4 __attribute__((ext_vector_type(4)));

// correctly-rounded t/3 (Markstein), 3 ops vs ~9-inst div expansion
__device__ __forceinline__ float div3(float t) {
    const float c = 0x1.555556p-2f;  // RN(1/3)
    float q0 = t * c;
    float r  = __builtin_fmaf(q0, -3.0f, t);
    return __builtin_fmaf(r, c, q0);
}

#define VMWAIT(N)                                         \
    asm volatile("s_waitcnt vmcnt(" #N ")" ::: "memory"); \
    __builtin_amdgcn_sched_barrier(0)

__global__ __launch_bounds__(128, 4)
void pixel_effect_kernel(const float* __restrict__ rgb, float* __restrict__ out) {
    __shared__ float ldsA[BUF_F];
    __shared__ float ldsB[BUF_F];

    const int tid  = threadIdx.x;       // 0..127
    const int wv   = tid >> 6;          // wave 0/1 -- fully independent
    const int lane = tid & 63;
    const int sub  = lane >> 4;         // row-sub 0..3
    const int cl   = lane & 15;         // cell within 16-cell tile

    float* __restrict__ ldsf = wv ? ldsB : ldsA;

    // XCD swizzle (grid 2048 = 8*256, bijective): XCD (wgid&7) owns one full
    // 32-cell strip column (256 rows) -> vertical halo overlap stays in-XCD.
    u32 wgid = blockIdx.x;
    u32 slot = (wgid & 7u) * 256u + (wgid >> 3);
    const int strip = (int)(slot >> 8);      // 0..7 (32-cell strips)
    const int oy    = (int)(slot & 255u);

    const int sstart = strip * 256 + wv * 128;   // first float col of wave's span
    const int xstart = sstart ? sstart - 8 : 0;  // staged 144-float span
    const int ox     = (sstart >> 3) + cl;
    const int ytop   = oy * 8 - 5;

    // ---- DMA stage: 1221 slots row-major (r*3+ch blocks of 37) ----
#pragma unroll
    for (int it = 0; it < ITERS; ++it) {
        u32 s = (u32)it * 64u + (u32)lane;
        s = s < (NSLOT - 1) ? s : (NSLOT - 1);      // tail -> last slot (junk)
        u32 blk = s / PITCH;
        u32 wp  = s - blk * PITCH;                  // slot-in-block 0..36
        u32 r   = blk / 3u;
        u32 ch  = blk - r * 3u;
        u32 wl  = wp < 36u ? wp : 35u;              // pad slot -> junk source
        int y = ytop + (int)r; y = y < 0 ? 0 : y;   // clamped rows unread
        long o = (long)ch * HW + (long)y * Wd + (long)(xstart + (int)(wl * 4u));
        long omax = 3L * HW - 4;                    // right-edge halo clamp
        o = o < omax ? o : omax;                    // (clamped chunks unread)
        float* ldst = ldsf + (u32)it * 256u;        // wave-uniform base
        __builtin_amdgcn_global_load_lds(
            (const __attribute__((address_space(1))) void*)(rgb + o),
            (__attribute__((address_space(3))) void*)ldst, 16, 0, 0);
    }

    const int w0    = (sstart == 0) ? (cl ? 2 * cl - 2 : 0) : 2 * cl;
    const u32 vmask = (sstart == 0 && cl == 0) ? 0x003Fu : 0x3FF8u;

    u64 c64 = 0;
    u32 nbl[3], nbh[3];

    // process row (4*kk + sub): 12 b128 reads + bin/count/nibble
#define PROC(kk)                                                               \
    {                                                                          \
        int r = 4 * (kk) + sub;                                                \
        nbl[kk] = 0xFFFFFFFFu; nbh[kk] = 0xFFFFFFFFu;                          \
        if (r <= 10 && ytop + r >= 0) {                                        \
            u32 bl = 0, bh = 0;                                                \
            _Pragma("unroll")                                                  \
            for (int q = 0; q < 4; ++q) {                                      \
                f32x4 r4 = *(const f32x4*)&ldsf[(u32)((r*3+0)*PITCH+w0+q)*4u]; \
                f32x4 g4 = *(const f32x4*)&ldsf[(u32)((r*3+1)*PITCH+w0+q)*4u]; \
                f32x4 b4 = *(const f32x4*)&ldsf[(u32)((r*3+2)*PITCH+w0+q)*4u]; \
                _Pragma("unroll")                                              \
                for (int jj = 0; jj < 4; ++jj) {                               \
                    int j = 4 * q + jj;                                        \
                    float m = div3(r4[jj] + g4[jj] + b4[jj]);                  \
                    u32 bin = (u32)(m * 0.03125f);                             \
                    u32 valid = (j < 14) ? ((vmask >> j) & 1u) : 0u;           \
                    c64 += (u64)valid << (bin << 3);                           \
                    u32 binv = valid ? bin : 15u;                              \
                    if (j < 8) bl |= binv << (4 * j);                          \
                    else if (j < 16) bh |= binv << (4 * (j - 8));              \
                }                                                              \
            }                                                                  \
            nbl[kk] = bl; nbh[kk] = bh;                                        \
        }                                                                      \
    }

    // ---- pass 1, progressive: rows<=3 after 7 iters, <=7 after 14, all 20 ----
    VMWAIT(13); PROC(0)
    VMWAIT(6);  PROC(1)
    VMWAIT(0);  PROC(2)

    // ---- reduce counts across 4 subs (lane bits 4,5); argmax first-max ----
    c64 += __shfl_xor(c64, 16);
    c64 += __shfl_xor(c64, 32);
    u32 lo = (u32)c64, hi = (u32)(c64 >> 32);
    u32 best = 0, bc = lo & 0xFFu;
#pragma unroll
    for (int b = 1; b < 8; ++b) {
        u32 cb = ((b < 4 ? lo : hi) >> ((b & 3) * 8)) & 0xFFu;
        bool t = cb > bc;
        bc   = t ? cb : bc;
        best = t ? (u32)b : best;
    }

    // ---- pass 2: re-read LDS (all staged), sum winning bin via nibbles ----
    float sr = 0.f, sg = 0.f, sb = 0.f;
#pragma unroll
    for (int kk = 0; kk < 3; ++kk) {
        int r = 4 * kk + sub;
        if (r <= 10 && ytop + r >= 0) {
            u32 bl = nbl[kk], bh = nbh[kk];
#pragma unroll
            for (int q = 0; q < 4; ++q) {
                f32x4 r4 = *(const f32x4*)&ldsf[(u32)((r*3+0)*PITCH+w0+q)*4u];
                f32x4 g4 = *(const f32x4*)&ldsf[(u32)((r*3+1)*PITCH+w0+q)*4u];
                f32x4 b4 = *(const f32x4*)&ldsf[(u32)((r*3+2)*PITCH+w0+q)*4u];
#pragma unroll
                for (int jj = 0; jj < 4; ++jj) {
                    int j = 4 * q + jj;
                    if (j >= 14) continue;
                    u32 bin = ((j < 8) ? (bl >> (4 * j))
                                       : (bh >> (4 * (j - 8)))) & 0xFu;
                    float hm = (bin == best) ? 1.0f : 0.0f;
                    sr = __builtin_fmaf(hm, r4[jj], sr);
                    sg = __builtin_fmaf(hm, g4[jj], sg);
                    sb = __builtin_fmaf(hm, b4[jj], sb);
                }
            }
        }
    }
    sr += __shfl_xor(sr, 16);  sr += __shfl_xor(sr, 32);
    sg += __shfl_xor(sg, 16);  sg += __shfl_xor(sg, 32);
    sb += __shfl_xor(sb, 16);  sb += __shfl_xor(sb, 32);

    float fbc = (float)bc;
    float orv = sr / fbc, ogv = sg / fbc, obv = sb / fbc;

    // ---- write: sub s owns rows 2s,2s+1 of the 8x8 block, 2x float4 each ----
    size_t base = (size_t)(oy * 8 + 2 * sub) * Wd + (size_t)(ox * 8);
    float vals[3] = { orv, ogv, obv };
#pragma unroll
    for (int c = 0; c < 3; ++c) {
        float v = vals[c];
        float4 vv = make_float4(v, v, v, v);
        float* o0 = out + (size_t)c * HW + base;
        ((float4*)o0)[0] = vv;  ((float4*)o0)[1] = vv;
        float* o1 = o0 + Wd;
        ((float4*)o1)[0] = vv;  ((float4*)o1)[1] = vv;
    }
}

extern "C" void kernel_launch(void* const* d_in, const int* in_sizes, int n_in,
                              void* d_out, int out_size, void* d_ws, size_t ws_size,
                              hipStream_t stream) {
    const float* rgb = (const float*)d_in[0];
    float* out = (float*)d_out;
    dim3 block(128, 1, 1);                // 2 independent waves, 16 cells each
    dim3 grid(2048, 1, 1);                // 8 strips x 256 rows (XCD-swizzled)
    hipLaunchKernelGGL(pixel_effect_kernel, grid, block, 0, stream, rgb, out);
}

// Round 21
// 28.900 us; speedup vs baseline: 1.0003x; 1.0003x over previous
//
#include <hip/hip_runtime.h>

// PixelEffectModule: 8-bin intensity histogram over 11x11 windows at stride 8,
// argmax bin, output that bin's mean RGB, upsampled 8x8.
// Input: rgb (1,3,2048,2048) fp32 in [0,255). Output: (1,3,2048,2048) fp32.
//
// R21: wave-per-cell, NO LDS, NO barriers, NO DMA. R13-R20 (8 variants) all
// lost to R14's 25.2 us; the shared fixed cost is the LDS staging round-trip
// (DMA issue + drain + ds_reads) per tile at 2-4 waves/SIMD. Input is
// L2/L3-resident (timed-replay FETCH ~0), so read it directly, twice:
//  - lane = (row r=lane>>2, chunk q=lane&3): 3 global dwordx4 loads/wave
//    cover the 11x16 window x 3ch. Each load = 11 row-contiguous 64B
//    segments (lanes 44-63 clamp to row 10, masked). x-adjacent cells
//    (4 waves/WG) share half their span -> L1 hits.
//  - pass 1: 4 px/lane -> packed-u64 counts + 16b nibble cache; 64-lane
//    butterfly (6 u64 shfl_xor); argmax (verified first-max code).
//  - pass 2: straight from the 12 registers already holding the pixels
//    (no reload of any kind); 3 float butterflies; lanes 0-47 write the
//    8x8x3 block, one dwordx4 each (64B-pairable).
//  - VGPR ~45, LDS 0 -> 8 waves/SIMD reachable; issue-bound arithmetic
//    ~12 us. Math path components all verified (absmax 0.0 lineage).
// Pre-committed: dur >= 25 us -> plateau is structural, restore R14.

#define Wd 2048
#define HW (2048 * 2048)

typedef unsigned int u32;
typedef unsigned long long u64;
typedef float f32x4 __attribute__((ext_vector_type(4)));

// correctly-rounded t/3 (Markstein), 3 ops vs ~9-inst div expansion
__device__ __forceinline__ float div3(float t) {
    const float c = 0x1.555556p-2f;  // RN(1/3)
    float q0 = t * c;
    float r  = __builtin_fmaf(q0, -3.0f, t);
    return __builtin_fmaf(r, c, q0);
}

__global__ __launch_bounds__(256, 8)
void pixel_effect_kernel(const float* __restrict__ rgb, float* __restrict__ out) {
    const int tid  = threadIdx.x;
    const int widx = tid >> 6;          // wave 0..3 -> cell within WG group
    const int lane = tid & 63;

    // XCD swizzle (grid 16384 = 8*2048, bijective): XCD (wgid&7) owns slots
    // [2048*xcd, ...) = 32 contiguous cell-rows (8192 cells).
    u32 wgid = blockIdx.x;
    u32 slot = (wgid & 7u) * 2048u + (wgid >> 3);
    u32 cell = slot * 4u + (u32)widx;   // 4 x-consecutive cells per WG
    const int ox = (int)(cell & 255u);
    const int oy = (int)(cell >> 8);

    // lane -> (window row r, 4-float chunk q); lanes 44..63 clamp to row 10
    int r = lane >> 2;
    const int q = lane & 3;
    const bool lactive = (r < 11);
    r = lactive ? r : 10;

    const int ytop = oy * 8 - 5;
    int y = ytop + r;
    const bool rowok = (y >= 0) && lactive;   // top edge + clamp lanes masked
    y = y < 0 ? 0 : y;

    const int xbase = (ox == 0) ? 0 : ox * 8 - 8;   // 16-float span, 32B aligned
    const u32 vmask = (ox == 0) ? 0x003Fu : 0x3FF8u;

    // ---- 3 loads: whole window in registers (L1/L2-hot) ----
    const size_t off = (size_t)y * Wd + (size_t)(xbase + 4 * q);
    f32x4 r4 = *(const f32x4*)(rgb + off);
    f32x4 g4 = *(const f32x4*)(rgb + HW + off);
    f32x4 b4 = *(const f32x4*)(rgb + 2 * HW + off);

    // ---- pass 1: bin 4 pixels, packed byte counts + nibble cache ----
    u64 c64 = 0;
    u32 nib = 0;
    const int jb = 4 * q;               // this lane's first j slot
#pragma unroll
    for (int jj = 0; jj < 4; ++jj) {
        float m = div3(r4[jj] + g4[jj] + b4[jj]);
        u32 bin = (u32)(m * 0.03125f);        // trunc(mean/32), exact pow2
        u32 valid = rowok ? ((vmask >> (jb + jj)) & 1u) : 0u;
        c64 += (u64)valid << (bin << 3);
        u32 binv = valid ? bin : 15u;         // 15 matches no bin
        nib |= binv << (4 * jj);
    }

    // ---- 64-lane butterfly reduce of packed counts (fields <=121) ----
    c64 += __shfl_xor(c64, 1);
    c64 += __shfl_xor(c64, 2);
    c64 += __shfl_xor(c64, 4);
    c64 += __shfl_xor(c64, 8);
    c64 += __shfl_xor(c64, 16);
    c64 += __shfl_xor(c64, 32);

    // ---- argmax bin, first-max wins (matches jnp.argmax) ----
    u32 lo = (u32)c64, hi = (u32)(c64 >> 32);
    u32 best = 0, bc = lo & 0xFFu;
#pragma unroll
    for (int b = 1; b < 8; ++b) {
        u32 cb = ((b < 4 ? lo : hi) >> ((b & 3) * 8)) & 0xFFu;
        bool t = cb > bc;
        bc   = t ? cb : bc;
        best = t ? (u32)b : best;
    }

    // ---- pass 2: selective sum straight from registers ----
    float sr = 0.f, sg = 0.f, sb = 0.f;
#pragma unroll
    for (int jj = 0; jj < 4; ++jj) {
        u32 bin = (nib >> (4 * jj)) & 0xFu;
        float hm = (bin == best) ? 1.0f : 0.0f;
        sr = __builtin_fmaf(hm, r4[jj], sr);
        sg = __builtin_fmaf(hm, g4[jj], sg);
        sb = __builtin_fmaf(hm, b4[jj], sb);
    }
    sr += __shfl_xor(sr, 1);  sr += __shfl_xor(sr, 2);  sr += __shfl_xor(sr, 4);
    sr += __shfl_xor(sr, 8);  sr += __shfl_xor(sr, 16); sr += __shfl_xor(sr, 32);
    sg += __shfl_xor(sg, 1);  sg += __shfl_xor(sg, 2);  sg += __shfl_xor(sg, 4);
    sg += __shfl_xor(sg, 8);  sg += __shfl_xor(sg, 16); sg += __shfl_xor(sg, 32);
    sb += __shfl_xor(sb, 1);  sb += __shfl_xor(sb, 2);  sb += __shfl_xor(sb, 4);
    sb += __shfl_xor(sb, 8);  sb += __shfl_xor(sb, 16); sb += __shfl_xor(sb, 32);

    const float fbc = (float)bc;
    const float orv = sr / fbc, ogv = sg / fbc, obv = sb / fbc;

    // ---- write: lanes 0..47 = (ch, row, half), one float4 splat each ----
    if (lane < 48) {
        const int ch   = lane >> 4;          // 0..2
        const int rr   = (lane >> 1) & 7;    // block row 0..7
        const int half = lane & 1;           // left/right float4
        float v = (ch == 0) ? orv : ((ch == 1) ? ogv : obv);
        float4 vv = make_float4(v, v, v, v);
        float* o = out + (size_t)ch * HW
                 + (size_t)(oy * 8 + rr) * Wd + (size_t)(ox * 8 + half * 4);
        *(float4*)o = vv;
    }
}

extern "C" void kernel_launch(void* const* d_in, const int* in_sizes, int n_in,
                              void* d_out, int out_size, void* d_ws, size_t ws_size,
                              hipStream_t stream) {
    const float* rgb = (const float*)d_in[0];
    float* out = (float*)d_out;
    dim3 block(256, 1, 1);                // 4 waves; ONE WAVE = ONE CELL
    dim3 grid(16384, 1, 1);               // 65536 cells / 4 (XCD-swizzled)
    hipLaunchKernelGGL(pixel_effect_kernel, grid, block, 0, stream, rgb, out);
}

// Round 22
// 25.148 us; speedup vs baseline: 1.1495x; 1.1492x over previous
//
#include <hip/hip_runtime.h>

// PixelEffectModule: 8-bin intensity histogram over 11x11 windows at stride 8,
// argmax bin, output that bin's mean RGB, upsampled 8x8.
// Input: rgb (1,3,2048,2048) fp32 in [0,255). Output: (1,3,2048,2048) fp32.
//
// FINAL = R14 (measured best: 25.2 us, absmax 0.0). Structure: DMA-staged
// stage -> drain -> two-pass compute at 16-cell granularity.
//  - 16-cell tiles, 128-thread WGs (2 waves; wave = 16 cells x 4 parts in
//    16-lane quarters). LDS 18.9 KB -> 8 WG/CU reachable.
//  - input staged via global_load_lds (16B chunks, linear LDS dest,
//    swizzled global source): holds in-flight data in the DMA queue, not
//    VGPRs -- sidesteps the allocator's 64-VGPR pin (R6-R11: register
//    batches either spill, inflating WRITE_SIZE, or get re-sunk to serial).
//  - two-pass nibble-cache math: pass 1 bins pixels (packed-u64 counts,
//    4b/px bin cache), shfl(16/32)+LDS reduce, first-max argmax, pass 2
//    re-reads LDS and predicated-FMA sums the winning bin.
//  - XCD-aware bijective swizzle: 32 contiguous cell-rows per XCD.
// Plateau evidence (R13-R21): counted-vmcnt pipelines, double-buffering,
// 2-tile batching, progressive drains, VALU-single-pass, and zero-LDS
// wave-per-cell ALL land 25-31 us; no pipe >35% busy in any variant. The
// ~25 us wall is the per-tile latency phase structure, not a fixable
// counter-visible bottleneck at this granularity.

#define Wd 2048
#define HW (2048 * 2048)
#define CPR 34      // 16B chunks per staged row (136 floats)
#define CPC 374     // chunks per channel (11 * 34)
#define NCHK 1122   // total chunks (3 * 374)
#define PADC 1152   // padded chunk count (9 iters * 128 threads)

typedef unsigned int u32;
typedef unsigned long long u64;
typedef float f32x4 __attribute__((ext_vector_type(4)));

// correctly-rounded t/3 (Markstein), 3 ops vs ~9-inst div expansion
__device__ __forceinline__ float div3(float t) {
    const float c = 0x1.555556p-2f;  // RN(1/3)
    float q0 = t * c;
    float r  = __builtin_fmaf(q0, -3.0f, t);
    return __builtin_fmaf(r, c, q0);
}

// chunk bank swizzle (involution for w<34; 32,33 fixed points)
__device__ __forceinline__ u32 swz2(u32 w) { return w ^ ((w >> 3) & 3u); }

__global__ __launch_bounds__(128, 4)
void pixel_effect_kernel(const float* __restrict__ rgb, float* __restrict__ out) {
    __shared__ float  ldsf[PADC * 4];   // 18.4 KB staged tile
    __shared__ u64    sc[2][16];
    __shared__ float4 ss[2][16];

    const int tid  = threadIdx.x;       // 0..127
    const int lane = tid & 63;
    const int w    = tid >> 6;          // wave 0..1
    const int qid  = (tid >> 4) & 3;    // quarter within wave
    const int cl   = tid & 15;          // cell within 16-strip
    const int p    = w * 4 + qid;       // row-band part 0..7

    // XCD swizzle (grid 4096 = 8*512, bijective): XCD (wgid&7) owns slots
    // [512*xcd, 512*xcd+512) = 32 contiguous cell-rows.
    u32 wgid = blockIdx.x;
    u32 slot = (wgid & 7u) * 512u + (wgid >> 3);
    const int oy = (int)(slot >> 4);
    const int tx = (int)(slot & 15u);
    const int ox = tx * 16 + cl;

    const int xstart = tx ? (tx * 128 - 8) : 0;   // staged 136-float span
    const int ytop   = oy * 8 - 5;

    // ---- DMA stage: 1122 chunks global -> LDS (linear dest, pre-swz src) ----
#pragma unroll
    for (int it = 0; it < 9; ++it) {
        u32 cbase = (u32)it * 128u + (u32)(tid & ~63);  // wave-uniform
        u32 c = cbase + (u32)lane;
        c = c < (NCHK - 1) ? c : (NCHK - 1);            // clamp -> junk to pad
        u32 ch  = c / CPC;
        u32 rem = c - ch * CPC;
        u32 row = rem / CPR;
        u32 wph = rem - row * CPR;                      // physical chunk-in-row
        u32 wlog = swz2(wph);                           // logical chunk to fetch
        int y = ytop + (int)row; y = y < 0 ? 0 : y;     // clamped rows unread
        const float* gsrc = rgb + (size_t)ch * HW + (size_t)y * Wd
                          + (size_t)(xstart + (int)(wlog * 4u));
        float* ldst = &ldsf[cbase * 4u];                // wave-uniform base
        __builtin_amdgcn_global_load_lds(
            (const __attribute__((address_space(1))) void*)gsrc,
            (__attribute__((address_space(3))) void*)ldst, 16, 0, 0);
    }
    __syncthreads();   // drains vmcnt before barrier

    // slot j maps row-local x = lx_off + j. Interior: j in [3,13]; ox==0:
    // j in [0,5]. 16-float read [lx_off, lx_off+16) always within the row.
    const int lx_off = (ox == 0) ? 0 : (8 * ox - 8 - xstart);  // mult of 8
    const int w0     = lx_off >> 2;                            // even chunk idx
    const u32 vmask  = (ox == 0) ? 0x003Fu : 0x3FF8u;
    const int rs = (p < 3) ? 2 * p : (3 + p);  // first window-row of this part
    const int nr = (p < 3) ? 2 : 1;            // rows: 2,2,2,1,1,1,1,1

#define LOADROW(dst, chn, rr)                                                    \
    {                                                                            \
        int rb_ = ((chn) * 11 + (rr)) * CPR;                                     \
        *(f32x4*)((dst) + 0)  = *(const f32x4*)&ldsf[(u32)(rb_ + swz2(w0+0))*4u];\
        *(f32x4*)((dst) + 4)  = *(const f32x4*)&ldsf[(u32)(rb_ + swz2(w0+1))*4u];\
        *(f32x4*)((dst) + 8)  = *(const f32x4*)&ldsf[(u32)(rb_ + swz2(w0+2))*4u];\
        *(f32x4*)((dst) + 12) = *(const f32x4*)&ldsf[(u32)(rb_ + swz2(w0+3))*4u];\
    }

    // ---- pass 1: bin pixels, packed byte counts + nibble cache ----
    u64 c64 = 0;
    u32 nbl[2], nbh[2];
#pragma unroll
    for (int k = 0; k < 2; ++k) {
        nbl[k] = 0xFFFFFFFFu; nbh[k] = 0xFFFFFFFFu;
        int r = rs + k;
        int y = ytop + r;                      // uniform per quarter
        if (k < nr && y >= 0) {
            float vR[16], vG[16], vB[16];
            LOADROW(vR, 0, r) LOADROW(vG, 1, r) LOADROW(vB, 2, r)
            u32 bl = 0, bh = 0;
#pragma unroll
            for (int j = 0; j < 14; ++j) {
                float m = div3(vR[j] + vG[j] + vB[j]);
                u32 bin = (u32)(m * 0.03125f);     // trunc(mean/32), exact
                u32 valid = (vmask >> j) & 1u;
                c64 += (u64)valid << (bin << 3);
                u32 binv = valid ? bin : 15u;      // 15 matches no bin
                if (j < 8) bl |= binv << (4 * j);
                else       bh |= binv << (4 * (j - 8));
            }
            nbl[k] = bl; nbh[k] = bh;
        }
    }

    // ---- reduce counts: 4 parts within wave (xor16, xor32), then 2 waves ----
    c64 += __shfl_xor(c64, 16);
    c64 += __shfl_xor(c64, 32);
    if (qid == 0) sc[w][cl] = c64;
    __syncthreads();

    u64 tot = sc[0][cl] + sc[1][cl];           // bytes <= 121: no carries
    u32 lo = (u32)tot, hi = (u32)(tot >> 32);
    u32 best = 0, bc = lo & 0xFFu;
#pragma unroll
    for (int b = 1; b < 8; ++b) {
        u32 cb = ((b < 4 ? lo : hi) >> ((b & 3) * 8)) & 0xFFu;
        bool t = cb > bc;
        bc   = t ? cb : bc;
        best = t ? (u32)b : best;
    }

    // ---- pass 2: re-read LDS (cheap), sum winning bin via nibbles ----
    float sr = 0.f, sg = 0.f, sb = 0.f;
#pragma unroll
    for (int k = 0; k < 2; ++k) {
        int r = rs + k;
        int y = ytop + r;
        if (k < nr && y >= 0) {
            float vR[16], vG[16], vB[16];
            LOADROW(vR, 0, r) LOADROW(vG, 1, r) LOADROW(vB, 2, r)
            u32 bl = nbl[k], bh = nbh[k];
#pragma unroll
            for (int j = 0; j < 14; ++j) {
                u32 bin = ((j < 8) ? (bl >> (4 * j))
                                   : (bh >> (4 * (j - 8)))) & 0xFu;
                float hm = (bin == best) ? 1.0f : 0.0f;
                sr = __builtin_fmaf(hm, vR[j], sr);
                sg = __builtin_fmaf(hm, vG[j], sg);
                sb = __builtin_fmaf(hm, vB[j], sb);
            }
        }
    }
    sr += __shfl_xor(sr, 16);  sr += __shfl_xor(sr, 32);
    sg += __shfl_xor(sg, 16);  sg += __shfl_xor(sg, 32);
    sb += __shfl_xor(sb, 16);  sb += __shfl_xor(sb, 32);

    if (qid == 0) ss[w][cl] = make_float4(sr, sg, sb, 0.f);
    __syncthreads();

    float4 s0 = ss[0][cl], s1 = ss[1][cl];
    float fbc = (float)bc;
    float orv = (s0.x + s1.x) / fbc;
    float ogv = (s0.y + s1.y) / fbc;
    float obv = (s0.z + s1.z) / fbc;

    // ---- write: part p owns row p of the 8x8 block, 2x float4 per channel ----
    size_t base = (size_t)(oy * 8 + p) * Wd + (size_t)(ox * 8);
    float vals[3] = { orv, ogv, obv };
#pragma unroll
    for (int c = 0; c < 3; ++c) {
        float v = vals[c];
        float4 vv = make_float4(v, v, v, v);
        float* o = out + (size_t)c * HW + base;
        ((float4*)o)[0] = vv;
        ((float4*)o)[1] = vv;
    }
#undef LOADROW
}

extern "C" void kernel_launch(void* const* d_in, const int* in_sizes, int n_in,
                              void* d_out, int out_size, void* d_ws, size_t ws_size,
                              hipStream_t stream) {
    const float* rgb = (const float*)d_in[0];
    float* out = (float*)d_out;
    dim3 block(128, 1, 1);                // 2 waves; wave = 16 cells x 4 parts
    dim3 grid(4096, 1, 1);                // 16 strips/cell-row x 256 rows (swizzled)
    hipLaunchKernelGGL(pixel_effect_kernel, grid, block, 0, stream, rgb, out);
}